// Round 1
// baseline (270.361 us; speedup 1.0000x reference)
//
#include <hip/hip_runtime.h>

typedef unsigned short u16;
typedef unsigned int   u32;
typedef float  f32x4  __attribute__((ext_vector_type(4)));
typedef __bf16 bf16x8 __attribute__((ext_vector_type(8)));
typedef u16    u16x8  __attribute__((ext_vector_type(8)));

#define NB     1024      // batch rows (M)
#define NN     8193      // output cols (N) and true K
#define K2     8224      // K padded to multiple of 32
#define NSTEP  257       // K2/32
#define ABF_LEN 16672    // a padded (true length 16385)
#define NFRAG  1040      // precomputed B-fragment blocks

// workspace byte offsets (all 256-aligned)
#define OFF_BANDS 0u         // 3*2049*4   = 24588
#define OFF_BUF1  24832u     // 4097*4     = 16388
#define OFF_BUF2  41472u     // 8193*4     = 32772
#define OFF_ABF   74496u     // 16672*2    = 33344
#define OFF_BFRAG 108032u    // 1040*1024  = 1064960
#define OFF_UREV  1172992u   // 1024*8224*2 = 16842752  (total ~18.0 MB)

__device__ __forceinline__ u16 f2bf(float f) {
  u32 u = __builtin_bit_cast(u32, f);
  return (u16)((u + 0x7FFFu + ((u >> 16) & 1u)) >> 16);
}

// ---------------- kernel a construction ----------------
// bands[j][k] = MLP_j(xc[k]), xc[k] = x[8k] (row 0 of the broadcast grid), k<2049
__global__ void k_bands(const float* __restrict__ x,
                        const float* __restrict__ W1, const float* __restrict__ b1,
                        const float* __restrict__ W2, const float* __restrict__ b2,
                        const float* __restrict__ W3, const float* __restrict__ b3,
                        float* __restrict__ bands) {
  const int j = blockIdx.y;
  __shared__ float w2s[4096];
  __shared__ float w1s[64], b1s[64], b2s[64], w3s[64];
  for (int i = threadIdx.x; i < 4096; i += 256) w2s[i] = W2[j * 4096 + i];
  if (threadIdx.x < 64) {
    w1s[threadIdx.x] = W1[j * 64 + threadIdx.x];
    b1s[threadIdx.x] = b1[j * 64 + threadIdx.x];
    b2s[threadIdx.x] = b2[j * 64 + threadIdx.x];
    w3s[threadIdx.x] = W3[j * 64 + threadIdx.x];
  }
  __syncthreads();
  const int k = blockIdx.x * 256 + threadIdx.x;
  if (k >= 2049) return;
  const float xc = x[8 * k];
  float h1[64];
  #pragma unroll
  for (int o = 0; o < 64; ++o) h1[o] = tanhf(w1s[o] * xc + b1s[o]);
  float outv = b3[j];
  for (int o = 0; o < 64; ++o) {
    float acc = b2s[o];
    #pragma unroll
    for (int c = 0; c < 64; ++c) acc += w2s[o * 64 + c] * h1[c];
    outv += w3s[o] * tanhf(acc);
  }
  bands[j * 2049 + k] = outv;
}

// level 1: buf1[4097] = interp(band0), overlay band1 at [512, 2561)
__global__ void k_lvl1(const float* __restrict__ bands, float* __restrict__ buf1) {
  const int i = blockIdx.x * 256 + threadIdx.x;
  if (i >= 4097) return;
  const float* bd0 = bands;
  const float* bd1 = bands + 2049;
  float v = (i & 1) ? 0.5f * (bd0[i >> 1] + bd0[(i >> 1) + 1]) : bd0[i >> 1];
  if (i >= 512 && i < 2561) v = bd1[i - 512];
  buf1[i] = v;
}

// level 2: buf2[8193] = interp(buf1), overlay band2 at [1024, 3073)
__global__ void k_lvl2(const float* __restrict__ bands, const float* __restrict__ buf1,
                       float* __restrict__ buf2) {
  const int i = blockIdx.x * 256 + threadIdx.x;
  if (i >= 8193) return;
  const float* bd2 = bands + 2 * 2049;
  float v = (i & 1) ? 0.5f * (buf1[i >> 1] + buf1[(i >> 1) + 1]) : buf1[i >> 1];
  if (i >= 1024 && i < 3073) v = bd2[i - 1024];
  buf2[i] = v;
}

// level 3: abf[i] = bf16(interp(buf2)[i]) for i<=16384, zero pad to ABF_LEN
__global__ void k_lvl3(const float* __restrict__ buf2, u16* __restrict__ abf) {
  const int i = blockIdx.x * 256 + threadIdx.x;
  if (i >= ABF_LEN) return;
  float v = 0.f;
  if (i <= 16384)
    v = (i & 1) ? 0.5f * (buf2[i >> 1] + buf2[(i >> 1) + 1]) : buf2[i >> 1];
  abf[i] = f2bf(v);
}

// urev[b][j] = bf16(u[b][8192-j]) for j<=8192 else 0  (K padded to 8224)
__global__ void k_urev(const float* __restrict__ u, u16* __restrict__ urev) {
  const long total = (long)NB * 1028;  // chunks of 8
  for (long c = (long)blockIdx.x * 256 + threadIdx.x; c < total;
       c += (long)gridDim.x * 256) {
    const int b = (int)(c / 1028);
    const int j = (int)(c % 1028) * 8;
    u16x8 v;
    #pragma unroll
    for (int r = 0; r < 8; ++r) {
      const int jr = j + r;
      const float f = (jr <= 8192) ? u[(size_t)b * NN + 8192 - jr] : 0.f;
      v[r] = f2bf(f);
    }
    *(u16x8*)&urev[(size_t)b * K2 + j] = v;
  }
}

// Bfrag[t][lane][idx] = abf[16t + (lane&15) + 8*(lane>>4) + idx]
__global__ void k_bfrag(const u16* __restrict__ abf, u16* __restrict__ bfr) {
  const int g = blockIdx.x * 256 + threadIdx.x;
  if (g >= NFRAG * 64) return;
  const int t = g >> 6, l = g & 63;
  const int s = 16 * t + (l & 15) + ((l >> 4) << 3);
  u16x8 v;
  #pragma unroll
  for (int r = 0; r < 8; ++r) v[r] = abf[s + r];
  *(u16x8*)&bfr[(size_t)g * 8] = v;
}

// ---------------- main Hankel GEMM ----------------
__device__ __forceinline__ void gload16(const void* g, void* l) {
  __builtin_amdgcn_global_load_lds((__attribute__((address_space(1))) void*)(void*)g,
                                   (__attribute__((address_space(3))) void*)l, 16, 0, 0);
}

__global__ __launch_bounds__(256, 2) void k_gemm(const u16* __restrict__ urev,
                                                 const u16* __restrict__ bfrag,
                                                 float* __restrict__ out) {
  __shared__ u16 Ab[2][4096];  // [128 rows][32 k] bf16, 8KB per buffer
  __shared__ u16 Bb[2][4096];  // 8 fragment-KBs per buffer
  const int tid  = threadIdx.x;
  const int lane = tid & 63;
  const int wid  = tid >> 6;
  const int wr   = wid >> 1;   // 2x2 wave grid, each wave 64x64
  const int wc   = wid & 1;
  const int i0   = blockIdx.x * 128;
  const int b0   = blockIdx.y * 128;
  const int t0b  = i0 >> 4;

  f32x4 acc[4][4] = {};

  auto stage = [&](int buf, int t) {
    const int j0 = t << 5;
    #pragma unroll
    for (int r = 0; r < 2; ++r) {
      const int ch = (r << 8) + tid;        // 512 x 16B chunks
      const int row = ch >> 2, c = ch & 3;
      gload16(urev + ((size_t)(b0 + row) * K2 + j0 + (c << 3)), &Ab[buf][ch << 3]);
    }
    const u16* bsrc = bfrag + (((size_t)(t0b + (t << 1))) << 9);  // frag t0, 8KB run
    #pragma unroll
    for (int r = 0; r < 2; ++r) {
      const int ch = (r << 8) + tid;
      gload16(bsrc + (ch << 3), &Bb[buf][ch << 3]);
    }
  };

  auto compute = [&](int buf) {
    bf16x8 af[4], bfv[4];
    #pragma unroll
    for (int m = 0; m < 4; ++m) {
      const int row = (wr << 6) + (m << 4) + (lane & 15);
      af[m] = *reinterpret_cast<const bf16x8*>(&Ab[buf][(row << 5) + ((lane >> 4) << 3)]);
    }
    #pragma unroll
    for (int n = 0; n < 4; ++n)
      bfv[n] = *reinterpret_cast<const bf16x8*>(&Bb[buf][(((wc << 2) + n) << 9) + (lane << 3)]);
    #pragma unroll
    for (int m = 0; m < 4; ++m)
      #pragma unroll
      for (int n = 0; n < 4; ++n)
        acc[m][n] = __builtin_amdgcn_mfma_f32_16x16x32_bf16(af[m], bfv[n], acc[m][n], 0, 0, 0);
  };

  stage(0, 0);
  asm volatile("s_waitcnt vmcnt(0)" ::: "memory");
  __syncthreads();
  int cur = 0;
  for (int t = 0; t < NSTEP - 1; ++t) {
    stage(cur ^ 1, t + 1);
    compute(cur);
    asm volatile("s_waitcnt vmcnt(0)" ::: "memory");
    __syncthreads();
    cur ^= 1;
  }
  compute(cur);

  #pragma unroll
  for (int n = 0; n < 4; ++n) {
    const int col = i0 + (wc << 6) + (n << 4) + (lane & 15);
    if (col < NN) {
      #pragma unroll
      for (int m = 0; m < 4; ++m) {
        const int rowb = b0 + (wr << 6) + (m << 4) + ((lane >> 4) << 2);
        float* o = out + (size_t)rowb * NN + col;
        #pragma unroll
        for (int r = 0; r < 4; ++r) o[(size_t)r * NN] = acc[m][n][r];
      }
    }
  }
}

extern "C" void kernel_launch(void* const* d_in, const int* in_sizes, int n_in,
                              void* d_out, int out_size, void* d_ws, size_t ws_size,
                              hipStream_t stream) {
  (void)in_sizes; (void)n_in; (void)out_size; (void)ws_size;
  const float* u  = (const float*)d_in[0];
  const float* x  = (const float*)d_in[1];
  const float* W1 = (const float*)d_in[2];
  const float* b1 = (const float*)d_in[3];
  const float* W2 = (const float*)d_in[4];
  const float* b2 = (const float*)d_in[5];
  const float* W3 = (const float*)d_in[6];
  const float* b3 = (const float*)d_in[7];
  float* out = (float*)d_out;
  char*  ws  = (char*)d_ws;

  float* bands = (float*)(ws + OFF_BANDS);
  float* buf1  = (float*)(ws + OFF_BUF1);
  float* buf2  = (float*)(ws + OFF_BUF2);
  u16*   abf   = (u16*)(ws + OFF_ABF);
  u16*   bfr   = (u16*)(ws + OFF_BFRAG);
  u16*   urev  = (u16*)(ws + OFF_UREV);

  k_bands<<<dim3(9, 3), 256, 0, stream>>>(x, W1, b1, W2, b2, W3, b3, bands);
  k_lvl1<<<17, 256, 0, stream>>>(bands, buf1);
  k_lvl2<<<33, 256, 0, stream>>>(bands, buf1, buf2);
  k_lvl3<<<66, 256, 0, stream>>>(buf2, abf);
  k_urev<<<2048, 256, 0, stream>>>(u, urev);
  k_bfrag<<<260, 256, 0, stream>>>(abf, bfr);
  k_gemm<<<dim3(65, 8), 256, 0, stream>>>(urev, bfr, out);
}